// Round 20
// baseline (7145.098 us; speedup 1.0000x reference)
//
#include <hip/hip_runtime.h>
#include <stdint.h>

// ---------------------------------------------------------------------------
// 3-layer LSTM (B=256,S=512,H=512) + FC(96) -> FLOAT32 out. ROUND-20.
// Base: r19 (PASSED 6866us, best). r19 post-mortem: gmat scatter swizzle was
// the win (8-way -> spread); the WEIGHT swizzle was a regression (A-reads
// were natively 2-way/free -- row stride 516 words tiles all 32 banks; the
// XOR collapsed group starts to {0,8,16,24} = 4-way; counter 3.86e8->1.4e9).
// Delta vs r19: revert weight staging/reads to linear (r17); keep gmat swz.
// Sentinels (float out[0]): <5e8 ws-MB*1e6 | 2e12 launch-fail | 3e9 spin-cap.
// ---------------------------------------------------------------------------

#define NGRP 8
#define BPG 32
#define HD 512
#define SEQ 512
#define TCHUNK 64
#define RSLOTS (TCHUNK + 1)
#define TILE_H (BPG * HD)
#define KPAD 1032
#define NTHREADS 512
#define GROWPAD 132

typedef _Float16 f16x8 __attribute__((ext_vector_type(8)));
typedef float f32x4 __attribute__((ext_vector_type(4)));

constexpr size_t W0_OFF   = (size_t)1 << 16;
constexpr size_t W0_SZ    = (size_t)32 * 64 * 512 * 2;
constexpr size_t W1_OFF   = W0_OFF + W0_SZ;
constexpr size_t W1_SZ    = (size_t)32 * 64 * 1024 * 2;
constexpr size_t W2_OFF   = W1_OFF + W1_SZ;
constexpr size_t H2_OFF   = W2_OFF + W1_SZ;
constexpr size_t H2_SZ    = (size_t)2 * NGRP * TILE_H * 2;
constexpr size_t RING_OFF = H2_OFF + H2_SZ;
constexpr size_t RING_SZ  = (size_t)RSLOTS * NGRP * TILE_H * 2;
constexpr size_t SEQ0_OFF = RING_OFF + RING_SZ;
constexpr size_t SEQ0_SZ  = (size_t)NGRP * SEQ * TILE_H * 2;
constexpr size_t WS_NEED  = SEQ0_OFF + SEQ0_SZ;

__device__ inline float sigm(float v) { return 1.f / (1.f + __expf(-v)); }
__device__ inline float tanhf_(float v) {
  float av = fabsf(v);
  float e = __expf(-2.f * av);
  float t = (1.f - e) / (1.f + e);
  return copysignf(t, v);
}

template <int K>
__global__ void convw(const float* __restrict__ whh, const float* __restrict__ wih,
                      _Float16* __restrict__ dst) {
  const int i = blockIdx.x * blockDim.x + threadIdx.x;
  constexpr int TOT = 32 * 64 * K / 4;
  if (i >= TOT) return;
  const int kq = i % (K / 4);
  const int rr = i / (K / 4);
  const int cg = rr >> 6, r = rr & 63;
  const int grow = (r >> 4) * 512 + cg * 16 + (r & 15);
  const int k = kq * 4;
  const float* src = (k < 512) ? (whh + (size_t)grow * 512 + k)
                               : (wih + (size_t)grow * 512 + (k - 512));
  float4 v = *(const float4*)src;
  _Float16 o[4] = {(_Float16)v.x, (_Float16)v.y, (_Float16)v.z, (_Float16)v.w};
  *(uint64_t*)(dst + (size_t)i * 4) = *(const uint64_t*)o;
}

// ---- stage weights into LDS (LINEAR layout -- natively 2-way/free) ---------
template <int K>
__device__ inline void stage_w(const _Float16* __restrict__ src,
                               _Float16* __restrict__ wlds, int tid) {
  constexpr int C = 64 * K / 8;
#pragma unroll 4
  for (int ci = tid; ci < C; ci += NTHREADS) {
    const int r = ci / (K / 8);
    const int kc = (ci % (K / 8)) * 8;
    *(f16x8*)(wlds + (size_t)r * KPAD + kc) = *(const f16x8*)(src + (size_t)r * K + kc);
  }
}

// ---- wave's GEMM share: ONE B-slice, TWO A row-tiles (linear A, verified) --
template <int NS>
__device__ inline void do_gemm2(const _Float16* __restrict__ bbase,
                                const _Float16* __restrict__ wlds,
                                int aKoff, int bKoff, int lane, int gp, int nt,
                                f32x4& acc0, f32x4& acc1) {
  const int bcol = nt * 16 + (lane & 15);
  const int krow = (lane >> 4) * 8;
  const _Float16* arow0 = wlds + (size_t)(gp * 32 + (lane & 15)) * KPAD + aKoff + krow;
  const _Float16* arow1 = arow0 + (size_t)16 * KPAD;
  const _Float16* brow  = bbase + (size_t)bcol * HD + bKoff + krow;
  constexpr int CH = (NS > 8) ? 8 : NS;
#pragma unroll
  for (int base = 0; base < NS; base += CH) {
    f16x8 br[CH];
#pragma unroll
    for (int s = 0; s < CH; ++s) br[s] = *(const f16x8*)(brow + (base + s) * 32);
#pragma unroll
    for (int s = 0; s < CH; ++s) {
      f16x8 a0 = *(const f16x8*)(arow0 + (base + s) * 32);
      acc0 = __builtin_amdgcn_mfma_f32_16x16x32_f16(a0, br[s], acc0, 0, 0, 0);
      f16x8 a1 = *(const f16x8*)(arow1 + (base + s) * 32);
      acc1 = __builtin_amdgcn_mfma_f32_16x16x32_f16(a1, br[s], acc1, 0, 0, 0);
    }
  }
}

// ---- full barrier (agent fences) [verified rounds 2/3/13] ------------------
__device__ inline void group_barrier(unsigned* slots, int cg, unsigned target,
                                     int lane, int wave, bool& dead) {
  __syncthreads();
  if (wave == 0) {
    if (lane == 0) {
      __builtin_amdgcn_fence(__ATOMIC_RELEASE, "agent");
      __hip_atomic_store(&slots[cg], target, __ATOMIC_RELAXED, __HIP_MEMORY_SCOPE_AGENT);
    }
    if (!dead) {
      unsigned* myslot = &slots[lane & 31];
      int spins = 0;
      while (true) {
        unsigned v = __hip_atomic_load(myslot, __ATOMIC_RELAXED, __HIP_MEMORY_SCOPE_AGENT);
        if (__all((int)(v >= target))) break;
        __builtin_amdgcn_s_sleep(1);
        if (++spins > (1 << 22)) { dead = true; break; }
      }
    }
    if (lane == 0) __builtin_amdgcn_fence(__ATOMIC_ACQUIRE, "agent");
  }
  __syncthreads();
}

__global__ __launch_bounds__(NTHREADS, 2) void lstm3_kernel(
    const float* __restrict__ x,
    const float* __restrict__ wih0,
    const float* __restrict__ bih0, const float* __restrict__ bhh0,
    const float* __restrict__ bih1, const float* __restrict__ bhh1,
    const float* __restrict__ bih2, const float* __restrict__ bhh2,
    const float* __restrict__ wfc, const float* __restrict__ bfc,
    float* __restrict__ out, char* __restrict__ ws) {
  __shared__ __align__(16) char smem[149504];
  __shared__ unsigned door;
  _Float16* wlds = (_Float16*)smem;                 // [64][KPAD] fp16 (linear)
  float* biasLds = (float*)(smem + 132096);         // [64]
  float* w0Lds   = (float*)(smem + 132352);         // [64]
  float* gmat    = (float*)(smem + 132608);         // [32 batch][GROWPAD] swz
  float* gmatF   = (float*)(smem + 132608);

  const int bid = blockIdx.x;
  const int grp = bid & 7;
  const int cg  = bid >> 3;
  const int tid = threadIdx.x;
  const int lane = tid & 63;
  const int wave = tid >> 6;
  const int gp = wave & 1;
  const int nt = (wave >> 1) & 1;
  const int kh = wave >> 2;
  const int nbase = cg * 16;
  const int ab = tid >> 4;
  const int an = tid & 15;

  unsigned* barA = (unsigned*)ws + grp * 64;                 // LLC flags
  unsigned* barB = (unsigned*)(ws + 4096) + grp * 64;        // L2 flags
  const _Float16* wcv0 = (const _Float16*)(ws + W0_OFF) + (size_t)cg * 64 * 512;
  const _Float16* wcv1 = (const _Float16*)(ws + W1_OFF) + (size_t)cg * 64 * 1024;
  const _Float16* wcv2 = (const _Float16*)(ws + W2_OFF) + (size_t)cg * 64 * 1024;
  _Float16* h2b  = (_Float16*)(ws + H2_OFF);
  _Float16* ring = (_Float16*)(ws + RING_OFF);
  _Float16* seq0 = (_Float16*)(ws + SEQ0_OFF);

  unsigned barIdxA = 0;
  bool dead = false;
  if (tid == 0) door = 0;

  // ---- startup: XCD detect -------------------------------------------------
  int myxcc = 0;
  asm volatile("s_getreg_b32 %0, hwreg(HW_REG_XCC_ID)" : "=s"(myxcc));
  int* xcds = (int*)(ws + 2048);
  if (tid == 0) xcds[bid] = myxcc;
  group_barrier(barA, cg, ++barIdxA, lane, wave, dead);
  bool local = true, allsame = true;
  for (int j = 0; j < BPG; ++j) local = local && (xcds[grp + 8 * j] == myxcc);
  for (int j = 0; j < NGRP * BPG; ++j) allsame = allsame && (xcds[j] == myxcc);
  if (allsame) local = false;
  const bool fastok = local;

  auto seqTile  = [&](int t) { return seq0 + ((size_t)(grp * SEQ + t)) * TILE_H; };
  auto ringTile = [&](int t) { return ring + ((size_t)(t % RSLOTS) * NGRP + grp) * TILE_H; };
  auto h2Tile   = [&](int s) { return h2b + ((size_t)s * NGRP + grp) * TILE_H; };

  auto step = [&](const _Float16* recB, const _Float16* inB, float xv, float& cst,
                  _Float16* houtTile, bool skip,
                  const char* pf1, const char* pf2) {
    float pfacc = 0.f;
    if (pf1 != nullptr && tid < 128) {
      float4 v = ((const float4*)pf1)[tid];
      pfacc += v.x + v.y + v.z + v.w;
    }
    if (pf2 != nullptr && tid >= 128 && tid < 256) {
      float4 v = ((const float4*)pf2)[tid - 128];
      pfacc += v.x + v.y + v.z + v.w;
    }
    const bool phaseB = (inB != nullptr);
    const unsigned tgt = ++barIdxA;
    if (fastok) {
      if (wave == 0) {
        if (lane == 0) {
          *(volatile unsigned*)&barB[cg] = tgt;    // plain -> shared XCD L2
          __hip_atomic_store(&barA[cg], tgt, __ATOMIC_RELAXED, __HIP_MEMORY_SCOPE_AGENT);
        }
        if (!dead) {
          bool ok = false;
          const volatile unsigned* fs = &barB[lane & 31];
          for (int it = 0; it < 64 && !ok; ++it) {
            asm volatile("buffer_inv\ns_waitcnt vmcnt(0)" ::: "memory");
            unsigned v = *fs;
            ok = __all((int)(v >= tgt));
          }
          if (!ok) {
            unsigned* ss = &barA[lane & 31];
            int s2 = 0;
            while (true) {
              unsigned v = __hip_atomic_load(ss, __ATOMIC_RELAXED,
                                             __HIP_MEMORY_SCOPE_AGENT);
              if (__all((int)(v >= tgt))) break;
              __builtin_amdgcn_s_sleep(1);
              if (++s2 > (1 << 22)) { dead = true; break; }
            }
            asm volatile("buffer_inv\ns_waitcnt vmcnt(0)" ::: "memory");
          }
        }
        if (lane == 0)
          __hip_atomic_store(&door, tgt, __ATOMIC_RELEASE, __HIP_MEMORY_SCOPE_WORKGROUP);
      } else if (wave < 4 || !phaseB) {
        while (__hip_atomic_load(&door, __ATOMIC_ACQUIRE, __HIP_MEMORY_SCOPE_WORKGROUP)
               < tgt) {}
      }
    }
    f32x4 acc0 = {0.f, 0.f, 0.f, 0.f};
    f32x4 acc1 = {0.f, 0.f, 0.f, 0.f};
    if (!skip) {
      if (!phaseB) {
        do_gemm2<8>(recB, wlds, kh * 256, kh * 256, lane, gp, nt, acc0, acc1);
      } else {
        const _Float16* bb = kh ? inB : recB;
        do_gemm2<16>(bb, wlds, kh * 512, 0, lane, gp, nt, acc0, acc1);
      }
    }
    {
      // gmat swizzled: word = colb*GROWPAD + (row ^ ((colb&7)<<2))  [kept]
      const int r0 = (lane >> 4) * 4;
      const int colb = nt * 16 + (lane & 15);
      const int rb0 = kh * 64 + gp * 32;
      const int gx = (colb & 7) << 2;
      *(f32x4*)(gmat + (size_t)colb * GROWPAD + ((rb0 + r0) ^ gx))      = acc0;
      *(f32x4*)(gmat + (size_t)colb * GROWPAD + ((rb0 + 16 + r0) ^ gx)) = acc1;
    }
    asm volatile("" :: "v"(pfacc));
    __syncthreads();                       // (B) gmat ready
    const int gx2 = (ab & 7) << 2;
    float pre[4];
#pragma unroll
    for (int g = 0; g < 4; ++g) {
      float s = gmat[(size_t)ab * GROWPAD + ((g * 16 + an) ^ gx2)] +
                gmat[(size_t)ab * GROWPAD + ((64 + g * 16 + an) ^ gx2)];
      pre[g] = s + biasLds[g * 16 + an] + xv * w0Lds[g * 16 + an];
    }
    const float gi = sigm(pre[0]);
    const float gf = sigm(pre[1]);
    const float gg = tanhf_(pre[2]);
    const float go = sigm(pre[3]);
    cst = gf * cst + gi * gg;
    const float h = go * tanhf_(cst);
    houtTile[(size_t)ab * HD + nbase + an] = (_Float16)h;
    if (fastok) __syncthreads();           // (A) drains h to shared L2
    else group_barrier(barA, cg, tgt, lane, wave, dead);
  };

  // ---------------- phase A: layer 0 (K=512, input is scalar x) -------------
  stage_w<512>(wcv0, wlds, tid);
  if (tid < 64) {
    const int grow2 = (tid >> 4) * 512 + nbase + (tid & 15);
    biasLds[tid] = bih0[grow2] + bhh0[grow2];
    w0Lds[tid] = wih0[grow2];
  }
  __syncthreads();

  float c0 = 0.f;
  for (int t = 0; t < SEQ; ++t) {
    const _Float16* recB = t ? seqTile(t - 1) : seq0;
    const float xv = x[(size_t)(grp * 32 + ab) * SEQ + t];
    const char* pf1 = nullptr;
    if (t >= 384 && t < 448)  pf1 = (const char*)wcv1 + (size_t)(t - 384) * 2048;
    else if (t >= 448)        pf1 = (const char*)seqTile(t - 448) + (size_t)cg * 2048;
    step(recB, nullptr, xv, c0, seqTile(t), t == 0, pf1, nullptr);
  }
  const float c0sav = c0;
  const _Float16* h0tile = seqTile(SEQ - 1);

  // ---------------- phase B: layers 1+2 interleaved in chunks ---------------
  float c1 = c0sav, c2 = c0sav;
  for (int ch = 0; ch < SEQ / TCHUNK; ++ch) {
    // L1 sub-phase
    __syncthreads();
    stage_w<1024>(wcv1, wlds, tid);
    if (tid < 64) {
      const int grow2 = (tid >> 4) * 512 + nbase + (tid & 15);
      biasLds[tid] = bih1[grow2] + bhh1[grow2];
      w0Lds[tid] = 0.f;
    }
    __syncthreads();
    for (int tt = 0; tt < TCHUNK; ++tt) {
      const int t = ch * TCHUNK + tt;
      const _Float16* recB = t ? ringTile(t - 1) : h0tile;
      const char* pf1 = (const char*)wcv2 + (size_t)tt * 2048;
      step(recB, seqTile(t), 0.f, c1, ringTile(t), false, pf1, nullptr);
    }
    // L2 sub-phase
    __syncthreads();
    stage_w<1024>(wcv2, wlds, tid);
    if (tid < 64) {
      const int grow2 = (tid >> 4) * 512 + nbase + (tid & 15);
      biasLds[tid] = bih2[grow2] + bhh2[grow2];
      w0Lds[tid] = 0.f;
    }
    __syncthreads();
    const bool more = (ch + 1) < SEQ / TCHUNK;
    for (int tt = 0; tt < TCHUNK; ++tt) {
      const int t = ch * TCHUNK + tt;
      const _Float16* recB = t ? h2Tile((t - 1) & 1) : h0tile;
      const char* pf1 = more ? (const char*)seqTile((ch + 1) * TCHUNK + tt) +
                               (size_t)cg * 2048 : nullptr;
      const char* pf2 = more ? (const char*)wcv1 + (size_t)tt * 2048 : nullptr;
      step(recB, ringTile(t), 0.f, c2, h2Tile(t & 1), false, pf1, pf2);
    }
  }

  // final cross-block publish before FC (h2 read across blocks)
  group_barrier(barA, cg, ++barIdxA, lane, wave, dead);

  // ---------------- final FC: out[b,:] = h2[b,:] @ Wfc^T + bfc (FLOAT32) ----
  {
    const _Float16* h2 = h2Tile((SEQ - 1) & 1) + (size_t)cg * HD;
    if (tid < 384) {
      const int pc = tid >> 2, kq = tid & 3;
      const float* wrow = wfc + (size_t)pc * HD + kq * 128;
      const _Float16* hh = h2 + kq * 128;
      float a = 0.f;
#pragma unroll 8
      for (int k2 = 0; k2 < 128; ++k2) a += (float)hh[k2] * wrow[k2];
      gmatF[pc * 4 + kq] = a;
    }
    __syncthreads();
    if (tid < 96) {
      const float a = gmatF[tid * 4] + gmatF[tid * 4 + 1] + gmatF[tid * 4 + 2] +
                      gmatF[tid * 4 + 3] + bfc[tid];
      out[(size_t)(grp * 32 + cg) * 96 + tid] = a;
    }
    if (dead && tid == 0)
      out[(size_t)(grp * 32 + cg) * 96] = 3.0e9f;
  }
}

__global__ void ws_info_kernel(float* out, float v) { out[0] = v; }

extern "C" void kernel_launch(void* const* d_in, const int* in_sizes, int n_in,
                              void* d_out, int out_size, void* d_ws, size_t ws_size,
                              hipStream_t stream) {
  const float* x    = (const float*)d_in[0];
  const float* wih0 = (const float*)d_in[1];
  const float* whh0 = (const float*)d_in[2];
  const float* bih0 = (const float*)d_in[3];
  const float* bhh0 = (const float*)d_in[4];
  const float* wih1 = (const float*)d_in[5];
  const float* whh1 = (const float*)d_in[6];
  const float* bih1 = (const float*)d_in[7];
  const float* bhh1 = (const float*)d_in[8];
  const float* wih2 = (const float*)d_in[9];
  const float* whh2 = (const float*)d_in[10];
  const float* bih2 = (const float*)d_in[11];
  const float* bhh2 = (const float*)d_in[12];
  const float* wfc  = (const float*)d_in[13];
  const float* bfc  = (const float*)d_in[14];
  float* out = (float*)d_out;
  char* ws = (char*)d_ws;

  if (ws_size < WS_NEED) {
    hipLaunchKernelGGL(ws_info_kernel, dim3(1), dim3(1), 0, stream, out,
                       (float)(ws_size >> 20) * 1.0e6f);
    return;
  }

  hipMemsetAsync(ws, 0, 8192, stream);   // barA + xcd table + barB

  _Float16* w0d = (_Float16*)(ws + W0_OFF);
  _Float16* w1d = (_Float16*)(ws + W1_OFF);
  _Float16* w2d = (_Float16*)(ws + W2_OFF);
  hipLaunchKernelGGL((convw<512>),  dim3(32 * 64 * 512 / 4 / 256),  dim3(256), 0, stream,
                     whh0, whh0, w0d);
  hipLaunchKernelGGL((convw<1024>), dim3(32 * 64 * 1024 / 4 / 256), dim3(256), 0, stream,
                     whh1, wih1, w1d);
  hipLaunchKernelGGL((convw<1024>), dim3(32 * 64 * 1024 / 4 / 256), dim3(256), 0, stream,
                     whh2, wih2, w2d);

  void* args[] = {(void*)&x, (void*)&wih0, (void*)&bih0, (void*)&bhh0,
                  (void*)&bih1, (void*)&bhh1, (void*)&bih2, (void*)&bhh2,
                  (void*)&wfc, (void*)&bfc, (void*)&out, (void*)&ws};
  hipError_t e = hipLaunchCooperativeKernel((const void*)lstm3_kernel,
                                            dim3(NGRP * BPG), dim3(NTHREADS),
                                            args, 0, stream);
  if (e != hipSuccess) {
    hipLaunchKernelGGL(ws_info_kernel, dim3(1), dim3(1), 0, stream, out, 2.0e12f);
  }
}

// Round 21
// 6854.051 us; speedup vs baseline: 1.0425x; 1.0425x over previous
//
#include <hip/hip_runtime.h>
#include <stdint.h>

// ---------------------------------------------------------------------------
// 3-layer LSTM (B=256,S=512,H=512) + FC(96) -> FLOAT32 out. ROUND-21.
// Base: r19 (PASSED 6866us, BEST). r20 isolated the swizzles: weight-XOR is
// the winner despite raising SQ_LDS_BANK_CONFLICT (conflict cycles are hidden
// under sync latency; counter does not predict time here). r19 restored.
// Single delta vs r19: prefetch sink moved AFTER the h-store -- the 2KB
// touch-load no longer serializes before syncthreads(B); it gets the whole
// GEMM+scatter+sync+epilogue (~3us) to land. pfacc is data-dead: zero risk.
// Sentinels (float out[0]): <5e8 ws-MB*1e6 | 2e12 launch-fail | 3e9 spin-cap.
// ---------------------------------------------------------------------------

#define NGRP 8
#define BPG 32
#define HD 512
#define SEQ 512
#define TCHUNK 64
#define RSLOTS (TCHUNK + 1)
#define TILE_H (BPG * HD)
#define KPAD 1032
#define NTHREADS 512
#define GROWPAD 132

typedef _Float16 f16x8 __attribute__((ext_vector_type(8)));
typedef float f32x4 __attribute__((ext_vector_type(4)));

constexpr size_t W0_OFF   = (size_t)1 << 16;
constexpr size_t W0_SZ    = (size_t)32 * 64 * 512 * 2;
constexpr size_t W1_OFF   = W0_OFF + W0_SZ;
constexpr size_t W1_SZ    = (size_t)32 * 64 * 1024 * 2;
constexpr size_t W2_OFF   = W1_OFF + W1_SZ;
constexpr size_t H2_OFF   = W2_OFF + W1_SZ;
constexpr size_t H2_SZ    = (size_t)2 * NGRP * TILE_H * 2;
constexpr size_t RING_OFF = H2_OFF + H2_SZ;
constexpr size_t RING_SZ  = (size_t)RSLOTS * NGRP * TILE_H * 2;
constexpr size_t SEQ0_OFF = RING_OFF + RING_SZ;
constexpr size_t SEQ0_SZ  = (size_t)NGRP * SEQ * TILE_H * 2;
constexpr size_t WS_NEED  = SEQ0_OFF + SEQ0_SZ;

__device__ inline float sigm(float v) { return 1.f / (1.f + __expf(-v)); }
__device__ inline float tanhf_(float v) {
  float av = fabsf(v);
  float e = __expf(-2.f * av);
  float t = (1.f - e) / (1.f + e);
  return copysignf(t, v);
}

template <int K>
__global__ void convw(const float* __restrict__ whh, const float* __restrict__ wih,
                      _Float16* __restrict__ dst) {
  const int i = blockIdx.x * blockDim.x + threadIdx.x;
  constexpr int TOT = 32 * 64 * K / 4;
  if (i >= TOT) return;
  const int kq = i % (K / 4);
  const int rr = i / (K / 4);
  const int cg = rr >> 6, r = rr & 63;
  const int grow = (r >> 4) * 512 + cg * 16 + (r & 15);
  const int k = kq * 4;
  const float* src = (k < 512) ? (whh + (size_t)grow * 512 + k)
                               : (wih + (size_t)grow * 512 + (k - 512));
  float4 v = *(const float4*)src;
  _Float16 o[4] = {(_Float16)v.x, (_Float16)v.y, (_Float16)v.z, (_Float16)v.w};
  *(uint64_t*)(dst + (size_t)i * 4) = *(const uint64_t*)o;
}

// ---- stage weights into LDS with row-XOR swizzle (r19 winner) --------------
template <int K>
__device__ inline void stage_w(const _Float16* __restrict__ src,
                               _Float16* __restrict__ wlds, int tid) {
  constexpr int C = 64 * K / 8;
#pragma unroll 4
  for (int ci = tid; ci < C; ci += NTHREADS) {
    const int r = ci / (K / 8);
    const int kc = (ci % (K / 8)) * 8;
    *(f16x8*)(wlds + (size_t)r * KPAD + (kc ^ ((r & 7) << 3))) =
        *(const f16x8*)(src + (size_t)r * K + kc);
  }
}

// ---- wave's GEMM share: ONE B-slice, TWO A row-tiles; swizzled A-reads -----
template <int NS>
__device__ inline void do_gemm2(const _Float16* __restrict__ bbase,
                                const _Float16* __restrict__ wlds,
                                int aKoff, int bKoff, int lane, int gp, int nt,
                                f32x4& acc0, f32x4& acc1) {
  const int bcol = nt * 16 + (lane & 15);
  const int krow = (lane >> 4) * 8;
  const int ax = (lane & 7) << 3;          // rows r and r+16 share (r&7)
  const _Float16* arow0 = wlds + (size_t)(gp * 32 + (lane & 15)) * KPAD;
  const _Float16* arow1 = arow0 + (size_t)16 * KPAD;
  const _Float16* brow  = bbase + (size_t)bcol * HD + bKoff + krow;
  constexpr int CH = (NS > 8) ? 8 : NS;
#pragma unroll
  for (int base = 0; base < NS; base += CH) {
    f16x8 br[CH];
#pragma unroll
    for (int s = 0; s < CH; ++s) br[s] = *(const f16x8*)(brow + (base + s) * 32);
#pragma unroll
    for (int s = 0; s < CH; ++s) {
      const int aoff = (aKoff + krow + (base + s) * 32) ^ ax;
      f16x8 a0 = *(const f16x8*)(arow0 + aoff);
      acc0 = __builtin_amdgcn_mfma_f32_16x16x32_f16(a0, br[s], acc0, 0, 0, 0);
      f16x8 a1 = *(const f16x8*)(arow1 + aoff);
      acc1 = __builtin_amdgcn_mfma_f32_16x16x32_f16(a1, br[s], acc1, 0, 0, 0);
    }
  }
}

// ---- full barrier (agent fences) [verified rounds 2/3/13] ------------------
__device__ inline void group_barrier(unsigned* slots, int cg, unsigned target,
                                     int lane, int wave, bool& dead) {
  __syncthreads();
  if (wave == 0) {
    if (lane == 0) {
      __builtin_amdgcn_fence(__ATOMIC_RELEASE, "agent");
      __hip_atomic_store(&slots[cg], target, __ATOMIC_RELAXED, __HIP_MEMORY_SCOPE_AGENT);
    }
    if (!dead) {
      unsigned* myslot = &slots[lane & 31];
      int spins = 0;
      while (true) {
        unsigned v = __hip_atomic_load(myslot, __ATOMIC_RELAXED, __HIP_MEMORY_SCOPE_AGENT);
        if (__all((int)(v >= target))) break;
        __builtin_amdgcn_s_sleep(1);
        if (++spins > (1 << 22)) { dead = true; break; }
      }
    }
    if (lane == 0) __builtin_amdgcn_fence(__ATOMIC_ACQUIRE, "agent");
  }
  __syncthreads();
}

__global__ __launch_bounds__(NTHREADS, 2) void lstm3_kernel(
    const float* __restrict__ x,
    const float* __restrict__ wih0,
    const float* __restrict__ bih0, const float* __restrict__ bhh0,
    const float* __restrict__ bih1, const float* __restrict__ bhh1,
    const float* __restrict__ bih2, const float* __restrict__ bhh2,
    const float* __restrict__ wfc, const float* __restrict__ bfc,
    float* __restrict__ out, char* __restrict__ ws) {
  __shared__ __align__(16) char smem[149504];
  __shared__ unsigned door;
  _Float16* wlds = (_Float16*)smem;                 // [64][KPAD] fp16 (swizzled)
  float* biasLds = (float*)(smem + 132096);         // [64]
  float* w0Lds   = (float*)(smem + 132352);         // [64]
  float* gmat    = (float*)(smem + 132608);         // [32 batch][GROWPAD] swz
  float* gmatF   = (float*)(smem + 132608);

  const int bid = blockIdx.x;
  const int grp = bid & 7;
  const int cg  = bid >> 3;
  const int tid = threadIdx.x;
  const int lane = tid & 63;
  const int wave = tid >> 6;
  const int gp = wave & 1;
  const int nt = (wave >> 1) & 1;
  const int kh = wave >> 2;
  const int nbase = cg * 16;
  const int ab = tid >> 4;
  const int an = tid & 15;

  unsigned* barA = (unsigned*)ws + grp * 64;                 // LLC flags
  unsigned* barB = (unsigned*)(ws + 4096) + grp * 64;        // L2 flags
  const _Float16* wcv0 = (const _Float16*)(ws + W0_OFF) + (size_t)cg * 64 * 512;
  const _Float16* wcv1 = (const _Float16*)(ws + W1_OFF) + (size_t)cg * 64 * 1024;
  const _Float16* wcv2 = (const _Float16*)(ws + W2_OFF) + (size_t)cg * 64 * 1024;
  _Float16* h2b  = (_Float16*)(ws + H2_OFF);
  _Float16* ring = (_Float16*)(ws + RING_OFF);
  _Float16* seq0 = (_Float16*)(ws + SEQ0_OFF);

  unsigned barIdxA = 0;
  bool dead = false;
  if (tid == 0) door = 0;

  // ---- startup: XCD detect -------------------------------------------------
  int myxcc = 0;
  asm volatile("s_getreg_b32 %0, hwreg(HW_REG_XCC_ID)" : "=s"(myxcc));
  int* xcds = (int*)(ws + 2048);
  if (tid == 0) xcds[bid] = myxcc;
  group_barrier(barA, cg, ++barIdxA, lane, wave, dead);
  bool local = true, allsame = true;
  for (int j = 0; j < BPG; ++j) local = local && (xcds[grp + 8 * j] == myxcc);
  for (int j = 0; j < NGRP * BPG; ++j) allsame = allsame && (xcds[j] == myxcc);
  if (allsame) local = false;
  const bool fastok = local;

  auto seqTile  = [&](int t) { return seq0 + ((size_t)(grp * SEQ + t)) * TILE_H; };
  auto ringTile = [&](int t) { return ring + ((size_t)(t % RSLOTS) * NGRP + grp) * TILE_H; };
  auto h2Tile   = [&](int s) { return h2b + ((size_t)s * NGRP + grp) * TILE_H; };

  auto step = [&](const _Float16* recB, const _Float16* inB, float xv, float& cst,
                  _Float16* houtTile, bool skip,
                  const char* pf1, const char* pf2) {
    float pfacc = 0.f;
    if (pf1 != nullptr && tid < 128) {
      float4 v = ((const float4*)pf1)[tid];
      pfacc += v.x + v.y + v.z + v.w;
    }
    if (pf2 != nullptr && tid >= 128 && tid < 256) {
      float4 v = ((const float4*)pf2)[tid - 128];
      pfacc += v.x + v.y + v.z + v.w;
    }
    const bool phaseB = (inB != nullptr);
    const unsigned tgt = ++barIdxA;
    if (fastok) {
      if (wave == 0) {
        if (lane == 0) {
          *(volatile unsigned*)&barB[cg] = tgt;    // plain -> shared XCD L2
          __hip_atomic_store(&barA[cg], tgt, __ATOMIC_RELAXED, __HIP_MEMORY_SCOPE_AGENT);
        }
        if (!dead) {
          bool ok = false;
          const volatile unsigned* fs = &barB[lane & 31];
          for (int it = 0; it < 64 && !ok; ++it) {
            asm volatile("buffer_inv\ns_waitcnt vmcnt(0)" ::: "memory");
            unsigned v = *fs;
            ok = __all((int)(v >= tgt));
          }
          if (!ok) {
            unsigned* ss = &barA[lane & 31];
            int s2 = 0;
            while (true) {
              unsigned v = __hip_atomic_load(ss, __ATOMIC_RELAXED,
                                             __HIP_MEMORY_SCOPE_AGENT);
              if (__all((int)(v >= tgt))) break;
              __builtin_amdgcn_s_sleep(1);
              if (++s2 > (1 << 22)) { dead = true; break; }
            }
            asm volatile("buffer_inv\ns_waitcnt vmcnt(0)" ::: "memory");
          }
        }
        if (lane == 0)
          __hip_atomic_store(&door, tgt, __ATOMIC_RELEASE, __HIP_MEMORY_SCOPE_WORKGROUP);
      } else if (wave < 4 || !phaseB) {
        while (__hip_atomic_load(&door, __ATOMIC_ACQUIRE, __HIP_MEMORY_SCOPE_WORKGROUP)
               < tgt) {}
      }
    }
    f32x4 acc0 = {0.f, 0.f, 0.f, 0.f};
    f32x4 acc1 = {0.f, 0.f, 0.f, 0.f};
    if (!skip) {
      if (!phaseB) {
        do_gemm2<8>(recB, wlds, kh * 256, kh * 256, lane, gp, nt, acc0, acc1);
      } else {
        const _Float16* bb = kh ? inB : recB;
        do_gemm2<16>(bb, wlds, kh * 512, 0, lane, gp, nt, acc0, acc1);
      }
    }
    {
      // gmat swizzled: word = colb*GROWPAD + (row ^ ((colb&7)<<2))
      const int r0 = (lane >> 4) * 4;
      const int colb = nt * 16 + (lane & 15);
      const int rb0 = kh * 64 + gp * 32;
      const int gx = (colb & 7) << 2;
      *(f32x4*)(gmat + (size_t)colb * GROWPAD + ((rb0 + r0) ^ gx))      = acc0;
      *(f32x4*)(gmat + (size_t)colb * GROWPAD + ((rb0 + 16 + r0) ^ gx)) = acc1;
    }
    __syncthreads();                       // (B) gmat ready
    const int gx2 = (ab & 7) << 2;
    float pre[4];
#pragma unroll
    for (int g = 0; g < 4; ++g) {
      float s = gmat[(size_t)ab * GROWPAD + ((g * 16 + an) ^ gx2)] +
                gmat[(size_t)ab * GROWPAD + ((64 + g * 16 + an) ^ gx2)];
      pre[g] = s + biasLds[g * 16 + an] + xv * w0Lds[g * 16 + an];
    }
    const float gi = sigm(pre[0]);
    const float gf = sigm(pre[1]);
    const float gg = tanhf_(pre[2]);
    const float go = sigm(pre[3]);
    cst = gf * cst + gi * gg;
    const float h = go * tanhf_(cst);
    houtTile[(size_t)ab * HD + nbase + an] = (_Float16)h;
    // ROUND-21: prefetch sink moved LATE -- the touch-load had the whole
    // GEMM+scatter+sync+epilogue to land; no serialized wait pre-sync(B).
    asm volatile("" :: "v"(pfacc));
    if (fastok) __syncthreads();           // (A) drains h to shared L2
    else group_barrier(barA, cg, tgt, lane, wave, dead);
  };

  // ---------------- phase A: layer 0 (K=512, input is scalar x) -------------
  stage_w<512>(wcv0, wlds, tid);
  if (tid < 64) {
    const int grow2 = (tid >> 4) * 512 + nbase + (tid & 15);
    biasLds[tid] = bih0[grow2] + bhh0[grow2];
    w0Lds[tid] = wih0[grow2];
  }
  __syncthreads();

  float c0 = 0.f;
  for (int t = 0; t < SEQ; ++t) {
    const _Float16* recB = t ? seqTile(t - 1) : seq0;
    const float xv = x[(size_t)(grp * 32 + ab) * SEQ + t];
    const char* pf1 = nullptr;
    if (t >= 384 && t < 448)  pf1 = (const char*)wcv1 + (size_t)(t - 384) * 2048;
    else if (t >= 448)        pf1 = (const char*)seqTile(t - 448) + (size_t)cg * 2048;
    step(recB, nullptr, xv, c0, seqTile(t), t == 0, pf1, nullptr);
  }
  const float c0sav = c0;
  const _Float16* h0tile = seqTile(SEQ - 1);

  // ---------------- phase B: layers 1+2 interleaved in chunks ---------------
  float c1 = c0sav, c2 = c0sav;
  for (int ch = 0; ch < SEQ / TCHUNK; ++ch) {
    // L1 sub-phase
    __syncthreads();
    stage_w<1024>(wcv1, wlds, tid);
    if (tid < 64) {
      const int grow2 = (tid >> 4) * 512 + nbase + (tid & 15);
      biasLds[tid] = bih1[grow2] + bhh1[grow2];
      w0Lds[tid] = 0.f;
    }
    __syncthreads();
    for (int tt = 0; tt < TCHUNK; ++tt) {
      const int t = ch * TCHUNK + tt;
      const _Float16* recB = t ? ringTile(t - 1) : h0tile;
      const char* pf1 = (const char*)wcv2 + (size_t)tt * 2048;
      step(recB, seqTile(t), 0.f, c1, ringTile(t), false, pf1, nullptr);
    }
    // L2 sub-phase
    __syncthreads();
    stage_w<1024>(wcv2, wlds, tid);
    if (tid < 64) {
      const int grow2 = (tid >> 4) * 512 + nbase + (tid & 15);
      biasLds[tid] = bih2[grow2] + bhh2[grow2];
      w0Lds[tid] = 0.f;
    }
    __syncthreads();
    const bool more = (ch + 1) < SEQ / TCHUNK;
    for (int tt = 0; tt < TCHUNK; ++tt) {
      const int t = ch * TCHUNK + tt;
      const _Float16* recB = t ? h2Tile((t - 1) & 1) : h0tile;
      const char* pf1 = more ? (const char*)seqTile((ch + 1) * TCHUNK + tt) +
                               (size_t)cg * 2048 : nullptr;
      const char* pf2 = more ? (const char*)wcv1 + (size_t)tt * 2048 : nullptr;
      step(recB, ringTile(t), 0.f, c2, h2Tile(t & 1), false, pf1, pf2);
    }
  }

  // final cross-block publish before FC (h2 read across blocks)
  group_barrier(barA, cg, ++barIdxA, lane, wave, dead);

  // ---------------- final FC: out[b,:] = h2[b,:] @ Wfc^T + bfc (FLOAT32) ----
  {
    const _Float16* h2 = h2Tile((SEQ - 1) & 1) + (size_t)cg * HD;
    if (tid < 384) {
      const int pc = tid >> 2, kq = tid & 3;
      const float* wrow = wfc + (size_t)pc * HD + kq * 128;
      const _Float16* hh = h2 + kq * 128;
      float a = 0.f;
#pragma unroll 8
      for (int k2 = 0; k2 < 128; ++k2) a += (float)hh[k2] * wrow[k2];
      gmatF[pc * 4 + kq] = a;
    }
    __syncthreads();
    if (tid < 96) {
      const float a = gmatF[tid * 4] + gmatF[tid * 4 + 1] + gmatF[tid * 4 + 2] +
                      gmatF[tid * 4 + 3] + bfc[tid];
      out[(size_t)(grp * 32 + cg) * 96 + tid] = a;
    }
    if (dead && tid == 0)
      out[(size_t)(grp * 32 + cg) * 96] = 3.0e9f;
  }
}

__global__ void ws_info_kernel(float* out, float v) { out[0] = v; }

extern "C" void kernel_launch(void* const* d_in, const int* in_sizes, int n_in,
                              void* d_out, int out_size, void* d_ws, size_t ws_size,
                              hipStream_t stream) {
  const float* x    = (const float*)d_in[0];
  const float* wih0 = (const float*)d_in[1];
  const float* whh0 = (const float*)d_in[2];
  const float* bih0 = (const float*)d_in[3];
  const float* bhh0 = (const float*)d_in[4];
  const float* wih1 = (const float*)d_in[5];
  const float* whh1 = (const float*)d_in[6];
  const float* bih1 = (const float*)d_in[7];
  const float* bhh1 = (const float*)d_in[8];
  const float* wih2 = (const float*)d_in[9];
  const float* whh2 = (const float*)d_in[10];
  const float* bih2 = (const float*)d_in[11];
  const float* bhh2 = (const float*)d_in[12];
  const float* wfc  = (const float*)d_in[13];
  const float* bfc  = (const float*)d_in[14];
  float* out = (float*)d_out;
  char* ws = (char*)d_ws;

  if (ws_size < WS_NEED) {
    hipLaunchKernelGGL(ws_info_kernel, dim3(1), dim3(1), 0, stream, out,
                       (float)(ws_size >> 20) * 1.0e6f);
    return;
  }

  hipMemsetAsync(ws, 0, 8192, stream);   // barA + xcd table + barB

  _Float16* w0d = (_Float16*)(ws + W0_OFF);
  _Float16* w1d = (_Float16*)(ws + W1_OFF);
  _Float16* w2d = (_Float16*)(ws + W2_OFF);
  hipLaunchKernelGGL((convw<512>),  dim3(32 * 64 * 512 / 4 / 256),  dim3(256), 0, stream,
                     whh0, whh0, w0d);
  hipLaunchKernelGGL((convw<1024>), dim3(32 * 64 * 1024 / 4 / 256), dim3(256), 0, stream,
                     whh1, wih1, w1d);
  hipLaunchKernelGGL((convw<1024>), dim3(32 * 64 * 1024 / 4 / 256), dim3(256), 0, stream,
                     whh2, wih2, w2d);

  void* args[] = {(void*)&x, (void*)&wih0, (void*)&bih0, (void*)&bhh0,
                  (void*)&bih1, (void*)&bhh1, (void*)&bih2, (void*)&bhh2,
                  (void*)&wfc, (void*)&bfc, (void*)&out, (void*)&ws};
  hipError_t e = hipLaunchCooperativeKernel((const void*)lstm3_kernel,
                                            dim3(NGRP * BPG), dim3(NTHREADS),
                                            args, 0, stream);
  if (e != hipSuccess) {
    hipLaunchKernelGGL(ws_info_kernel, dim3(1), dim3(1), 0, stream, out, 2.0e12f);
  }
}